// Round 2
// baseline (110.462 us; speedup 1.0000x reference)
//
#include <hip/hip_runtime.h>
#include <math.h>

// PartialAttention: LN -> Q/K proj -> scaled QK^T -> rowmax-subtracted exp.
// S=4096, B=2, E=1024, D=64. Out [B,S,S] f32 = 134 MB.
//
// Kernel 1 (ln_proj): per block 16 rows: LN (wave reduce) -> proj (f32 FMA,
//   2x4 register tile) -> write q',k (q pre-scaled by 1/8) as bf16 hi/lo
//   MFMA-fragment-ordered arrays into d_ws (4 MB).
// Kernel 2 (score): per block (b, 16-row tile): 16 waves x 16 col-tiles of
//   16x16x32 bf16 MFMA, 3-term hi/lo split (hi*hi + hi*lo + lo*hi),
//   row-max via shfl_xor + LDS, exp, store.

typedef __attribute__((ext_vector_type(4))) float f32x4;
typedef __attribute__((ext_vector_type(8))) short bf16x8;
typedef __attribute__((ext_vector_type(8))) unsigned short u16x8;

#define SLEN 4096
#define BATCH 2
#define EDIM 1024
#define DDIM 64

#define XN_STRIDE 1028   // 1024 + 4 pad: bank = (4*row + e) % 32
#define QK_STRIDE 136    // q cols [0,64), k cols [68,132)

__device__ __forceinline__ unsigned short f2bf(float f) {
    unsigned int u = __float_as_uint(f);
    u += 0x7FFFu + ((u >> 16) & 1u);   // RNE truncate to bf16
    return (unsigned short)(u >> 16);
}
__device__ __forceinline__ float bf2f(unsigned short h) {
    return __uint_as_float(((unsigned int)h) << 16);
}

__global__ __launch_bounds__(256, 2) void ln_proj_kernel(
    const float* __restrict__ src, const float* __restrict__ gamma,
    const float* __restrict__ beta, const float* __restrict__ Wq,
    const float* __restrict__ bq, const float* __restrict__ Wk,
    const float* __restrict__ bk,
    unsigned short* __restrict__ qhf, unsigned short* __restrict__ qlf,
    unsigned short* __restrict__ khf, unsigned short* __restrict__ klf)
{
    __shared__ float xn[16 * XN_STRIDE];   // 64.25 KB; reused for q/k after proj
    const int tid  = threadIdx.x;
    const int lane = tid & 63;
    const int wv   = tid >> 6;
    const int bid  = blockIdx.x;           // 0..511: tile index
    const int b    = bid >> 8;
    const int s0   = (bid & 255) * 16;

    // ---- phase 1: LayerNorm, 4 rows per wave ----
    for (int ii = 0; ii < 4; ++ii) {
        const int i = wv * 4 + ii;
        const float* row = src + ((size_t)(s0 + i) * BATCH + b) * EDIM;
        float4 v[4];
        float sum = 0.f, sq = 0.f;
#pragma unroll
        for (int k = 0; k < 4; ++k) {
            v[k] = *reinterpret_cast<const float4*>(row + k * 256 + lane * 4);
            sum += v[k].x + v[k].y + v[k].z + v[k].w;
            sq  += v[k].x*v[k].x + v[k].y*v[k].y + v[k].z*v[k].z + v[k].w*v[k].w;
        }
#pragma unroll
        for (int off = 1; off < 64; off <<= 1) {
            sum += __shfl_xor(sum, off);
            sq  += __shfl_xor(sq,  off);
        }
        const float mu   = sum * (1.f / EDIM);
        const float rstd = rsqrtf(sq * (1.f / EDIM) - mu * mu + 1e-5f);
#pragma unroll
        for (int k = 0; k < 4; ++k) {
            const int e = k * 256 + lane * 4;
            float4 g  = *reinterpret_cast<const float4*>(gamma + e);
            float4 bt = *reinterpret_cast<const float4*>(beta + e);
            float4 o;
            o.x = (v[k].x - mu) * rstd * g.x + bt.x;
            o.y = (v[k].y - mu) * rstd * g.y + bt.y;
            o.z = (v[k].z - mu) * rstd * g.z + bt.z;
            o.w = (v[k].w - mu) * rstd * g.w + bt.w;
            *reinterpret_cast<float4*>(&xn[i * XN_STRIDE + e]) = o;
        }
    }
    __syncthreads();

    // ---- phase 2: projection. thread = (rg rows: rg*2+{0,1}) x (4 cols dg*4..) ----
    const int dg   = tid & 31;             // 0..15 -> Wq cols, 16..31 -> Wk cols
    const int rg   = tid >> 5;             // 0..7
    const float* Wm = (dg < 16) ? Wq : Wk;
    const int dcol = (dg & 15) * 4;
    float acc[2][4] = {};
    const float* x0p = &xn[(rg * 2 + 0) * XN_STRIDE];
    const float* x1p = &xn[(rg * 2 + 1) * XN_STRIDE];
#pragma unroll 2
    for (int e = 0; e < EDIM; e += 4) {
        float w[4][4];
#pragma unroll
        for (int i = 0; i < 4; ++i) {
            float4 t = *reinterpret_cast<const float4*>(Wm + (size_t)(e + i) * DDIM + dcol);
            w[i][0] = t.x; w[i][1] = t.y; w[i][2] = t.z; w[i][3] = t.w;
        }
        float4 xa = *reinterpret_cast<const float4*>(x0p + e);
        float4 xb = *reinterpret_cast<const float4*>(x1p + e);
        float xr[2][4] = {{xa.x, xa.y, xa.z, xa.w}, {xb.x, xb.y, xb.z, xb.w}};
#pragma unroll
        for (int r = 0; r < 2; ++r)
#pragma unroll
            for (int j = 0; j < 4; ++j) {
                acc[r][j] += xr[r][0] * w[0][j];
                acc[r][j] += xr[r][1] * w[1][j];
                acc[r][j] += xr[r][2] * w[2][j];
                acc[r][j] += xr[r][3] * w[3][j];
            }
    }
    const float* biasp = (dg < 16) ? bq : bk;
    float4 bv = *reinterpret_cast<const float4*>(biasp + dcol);
    __syncthreads();   // all xn reads done; reuse LDS for q/k
    float* qk = xn;
    const int colbase = (dg < 16) ? dcol : (68 + dcol);
#pragma unroll
    for (int r = 0; r < 2; ++r) {
        float4 o;
        o.x = acc[r][0] + bv.x;
        o.y = acc[r][1] + bv.y;
        o.z = acc[r][2] + bv.z;
        o.w = acc[r][3] + bv.w;
        *reinterpret_cast<float4*>(&qk[(rg * 2 + r) * QK_STRIDE + colbase]) = o;
    }
    __syncthreads();

    // ---- phase 3: hi/lo bf16 split, MFMA-fragment order, coalesced store ----
    // frag elem index: ((b*256 + tile)*2 + dc)*512 + lane*8 + j
    // value = v[tile*16 + (lane&15)][dc*32 + ((lane>>4)&3)*8 + j]
    {
        const int l2  = tid & 63;
        const int dc  = (tid >> 6) & 1;
        const int isK = tid >> 7;
        const int row = l2 & 15;
        const int d0  = dc * 32 + ((l2 >> 4) & 3) * 8;
        const float* p = &qk[row * QK_STRIDE + (isK ? 68 : 0) + d0];
        const float sc = isK ? 1.0f : 0.125f;   // fold 1/sqrt(D) into q
        u16x8 hvv, lvv;
#pragma unroll
        for (int j = 0; j < 8; ++j) {
            const float vq = p[j] * sc;
            const unsigned short h = f2bf(vq);
            hvv[j] = h;
            lvv[j] = f2bf(vq - bf2f(h));
        }
        const size_t base = ((((size_t)b * 256 + (size_t)(bid & 255)) * 2 + dc) * 512) + (size_t)l2 * 8;
        *reinterpret_cast<u16x8*>((isK ? khf : qhf) + base) = hvv;
        *reinterpret_cast<u16x8*>((isK ? klf : qlf) + base) = lvv;
    }
}

__global__ __launch_bounds__(1024, 1) void score_kernel(
    const unsigned short* __restrict__ qhf, const unsigned short* __restrict__ qlf,
    const unsigned short* __restrict__ khf, const unsigned short* __restrict__ klf,
    float* __restrict__ out)
{
    __shared__ float wmax[16 * 16];
    __shared__ float fmax_s[16];
    const int tid = threadIdx.x;
    const int l   = tid & 63;
    const int w   = tid >> 6;        // wave 0..15, owns col-tiles w*16..w*16+15
    const int bid = blockIdx.x;
    const int b   = bid >> 8;
    const int rt  = bid & 255;       // row tile (16 q rows)

    const size_t abase = (((size_t)b * 256 + rt) * 2) * 512 + (size_t)l * 8;
    const bf16x8 qh0 = *reinterpret_cast<const bf16x8*>(qhf + abase);
    const bf16x8 qh1 = *reinterpret_cast<const bf16x8*>(qhf + abase + 512);
    const bf16x8 ql0 = *reinterpret_cast<const bf16x8*>(qlf + abase);
    const bf16x8 ql1 = *reinterpret_cast<const bf16x8*>(qlf + abase + 512);

    f32x4 acc[16];
#pragma unroll
    for (int i = 0; i < 16; ++i) acc[i] = (f32x4){0.f, 0.f, 0.f, 0.f};

#pragma unroll
    for (int i = 0; i < 16; ++i) {
        const int ct = w * 16 + i;
        const size_t kb = (((size_t)b * 256 + ct) * 2) * 512 + (size_t)l * 8;
        const bf16x8 kh0 = *reinterpret_cast<const bf16x8*>(khf + kb);
        const bf16x8 kh1 = *reinterpret_cast<const bf16x8*>(khf + kb + 512);
        const bf16x8 kl0 = *reinterpret_cast<const bf16x8*>(klf + kb);
        const bf16x8 kl1 = *reinterpret_cast<const bf16x8*>(klf + kb + 512);
        f32x4 a = acc[i];
        a = __builtin_amdgcn_mfma_f32_16x16x32_bf16(qh0, kh0, a, 0, 0, 0);
        a = __builtin_amdgcn_mfma_f32_16x16x32_bf16(qh1, kh1, a, 0, 0, 0);
        a = __builtin_amdgcn_mfma_f32_16x16x32_bf16(qh0, kl0, a, 0, 0, 0);
        a = __builtin_amdgcn_mfma_f32_16x16x32_bf16(qh1, kl1, a, 0, 0, 0);
        a = __builtin_amdgcn_mfma_f32_16x16x32_bf16(ql0, kh0, a, 0, 0, 0);
        a = __builtin_amdgcn_mfma_f32_16x16x32_bf16(ql1, kh1, a, 0, 0, 0);
        acc[i] = a;
    }

    // row max: lane holds rows (l>>4)*4+r, col l&15; reduce over cols
    float m4[4];
#pragma unroll
    for (int r = 0; r < 4; ++r) {
        m4[r] = acc[0][r];
#pragma unroll
        for (int i = 1; i < 16; ++i) m4[r] = fmaxf(m4[r], acc[i][r]);
    }
#pragma unroll
    for (int off = 1; off < 16; off <<= 1) {
#pragma unroll
        for (int r = 0; r < 4; ++r) m4[r] = fmaxf(m4[r], __shfl_xor(m4[r], off));
    }
    const int rgrp = l >> 4;
    if ((l & 15) == 0) {
#pragma unroll
        for (int r = 0; r < 4; ++r) wmax[w * 16 + rgrp * 4 + r] = m4[r];
    }
    __syncthreads();
    if (tid < 16) {
        float m = wmax[tid];
#pragma unroll
        for (int ww = 1; ww < 16; ++ww) m = fmaxf(m, wmax[ww * 16 + tid]);
        fmax_s[tid] = m;
    }
    __syncthreads();

    float fm[4];
#pragma unroll
    for (int r = 0; r < 4; ++r) fm[r] = fmax_s[rgrp * 4 + r];
    const int cres = l & 15;
    const size_t obase = ((size_t)b * SLEN + (size_t)rt * 16) * SLEN;
#pragma unroll
    for (int i = 0; i < 16; ++i) {
        const int col = (w * 16 + i) * 16 + cres;
#pragma unroll
        for (int r = 0; r < 4; ++r)
            out[obase + (size_t)(rgrp * 4 + r) * SLEN + col] = __expf(acc[i][r] - fm[r]);
    }
}

extern "C" void kernel_launch(void* const* d_in, const int* in_sizes, int n_in,
                              void* d_out, int out_size, void* d_ws, size_t ws_size,
                              hipStream_t stream) {
    (void)in_sizes; (void)n_in; (void)out_size; (void)ws_size;
    const float* src   = (const float*)d_in[0];
    const float* gamma = (const float*)d_in[1];
    const float* beta  = (const float*)d_in[2];
    const float* Wq    = (const float*)d_in[3];
    const float* bq    = (const float*)d_in[4];
    const float* Wk    = (const float*)d_in[5];
    const float* bk    = (const float*)d_in[6];
    float* out = (float*)d_out;

    // ws: 4 arrays of 2*256*2*64*8 = 524288 bf16 (1 MB) each = 4 MB total
    unsigned short* ws  = (unsigned short*)d_ws;
    unsigned short* qhf = ws;
    unsigned short* qlf = ws + (1u << 19);
    unsigned short* khf = ws + (2u << 19);
    unsigned short* klf = ws + (3u << 19);

    hipLaunchKernelGGL(ln_proj_kernel, dim3(512), dim3(256), 0, stream,
                       src, gamma, beta, Wq, bq, Wk, bk, qhf, qlf, khf, klf);
    hipLaunchKernelGGL(score_kernel, dim3(512), dim3(1024), 0, stream,
                       qhf, qlf, khf, klf, out);
}